// Round 12
// baseline (253.843 us; speedup 1.0000x reference)
//
#include <hip/hip_runtime.h>
#include <hip/hip_bf16.h>
#include <stdint.h>

namespace {
constexpr int kH = 64;
constexpr int kIn = 9;
constexpr int kSrcLen = 7;
constexpr int kPredLen = 10;
constexpr int kRowsPerWave = 16;  // each wave owns 16 batch rows END-TO-END
constexpr int kWaves = 4;
constexpr int kRows = kRowsPerWave * kWaves;  // 64 rows per block
constexpr int kThreads = 256;
constexpr int kOutW = kPredLen * kIn;  // 90

// ROW DECOMPOSITION (barrier-free): wave w owns rows rw0..rw0+15 and computes
// ALL 64 hidden units for them. h never crosses waves -> no __syncthreads in
// the 17-step main loop (3 barriers total, all for weight staging).
// - Wl: pre-scaled f16 weights in LDS, row n (gate*64+unit) holds k 0..63 =
//   Whh', k 64..72 = Wih', k 73 = bias', k 74..79 = 0. Stride 80 halves =
//   160 B -> every b128 fragment read is 16B-aligned.
// - Tb[wave]: wave-private h transpose buffer [16 rows][68 halves] (stride 68
//   = 136 B: b64 reads 8B-aligned; write bank = (8q + 2j + 8ct + h/2)%32 ->
//   2-way = free). Written by activations, read back by the SAME wave for the
//   next step's A-fragments and the fc head. WAR is via registers (A-frags
//   are loaded before any write); RAW ordering is compiler lgkmcnt.
// - Pb[wave]: pred feedback panel [16 rows][20 halves]: cols 0..8 = pred,
//   col 9 = 1.0 (bias), 10..15 = 0 -> next step's a2 b64 read, wave-local.
constexpr int kWStride = 80;
constexpr int kTStride = 68;
constexpr int kPStride = 20;

constexpr float kLog2e = 1.4426950408889634f;
constexpr float k2Log2e = 2.8853900817779268f;

typedef __attribute__((ext_vector_type(8))) _Float16 frag_a;   // K=32 frag
typedef __attribute__((ext_vector_type(4))) _Float16 frag_a2;  // K=16 frag / half4
typedef __attribute__((ext_vector_type(4))) float frag_cd;     // 4 fp32 acc

__device__ __forceinline__ float fast_rcp(float x) { return __builtin_amdgcn_rcpf(x); }
__device__ __forceinline__ float exp2_f(float x) { return __builtin_amdgcn_exp2f(x); }

__device__ __forceinline__ float ldf(const void* p, int i, int isbf) {
  if (isbf) {
    uint32_t w = ((uint32_t)((const uint16_t*)p)[i]) << 16;
    float f; __builtin_memcpy(&f, &w, 4); return f;
  }
  return ((const float*)p)[i];
}
}  // namespace

// Detect whether inputs are bf16 or fp32 by sampling src.
extern "C" __global__ void detect_dtype_kernel(const uint16_t* __restrict__ src_u16,
                                               int* __restrict__ flag) {
  const int t = threadIdx.x;
  int bad = 0;
  for (int i = t; i < 256; i += 64) {
    const uint16_t u = src_u16[i];
    const uint32_t e = (u >> 7) & 0xFF;
    const int plausible = (u == 0) || (e >= 100 && e <= 150);
    bad += !plausible;
  }
#pragma unroll
  for (int off = 32; off; off >>= 1) bad += __shfl_down(bad, off, 64);
  if (t == 0) *flag = (bad < 64) ? 1 : 0;
}

extern "C" __global__ void __launch_bounds__(kThreads)
// min 3 waves/EU -> 170-reg RA budget. Weights moved to LDS so register
// demand collapses to ~90 (vs the col-decomposition's 124 that walled every
// prior occupancy attempt: r1/r3/r6/r7 all spilled at <128 budgets). LDS
// 52,224 B -> 3 blocks/CU. ARITHMETIC IS r8-VERBATIM (same pre-scale, same
// fused-rcp activations, same MFMA operand order) -> bit-identical output.
__attribute__((amdgpu_waves_per_eu(3, 4)))
lstm_seq2seq_kernel(const void* __restrict__ src,
                    const void* __restrict__ enc_Wih,
                    const void* __restrict__ enc_Whh,
                    const void* __restrict__ enc_b,
                    const void* __restrict__ dec_Wih,
                    const void* __restrict__ dec_Whh,
                    const void* __restrict__ dec_b,
                    const void* __restrict__ fc_W,
                    const void* __restrict__ fc_b,
                    void* __restrict__ out,
                    const int* __restrict__ flag) {
  __shared__ __align__(16) _Float16 Wl[4 * kH * kWStride];                  // 40,960 B
  __shared__ __align__(16) _Float16 Tb[kWaves][kRowsPerWave * kTStride];    //  8,704 B
  __shared__ __align__(16) _Float16 Pb[kWaves][kRowsPerWave * kPStride];    //  2,560 B

  const int tid = threadIdx.x;
  const int lane = tid & 63;
  const int wave = tid >> 6;
  const int quad = lane >> 4;
  const int half = lane & 15;
  const int rw0 = blockIdx.x * kRows + wave * kRowsPerWave;  // first owned row
  const int isbf = *flag;  // grid-uniform

  _Float16* Tw = &Tb[wave][0];
  _Float16* Pw = &Pb[wave][0];

  // ---- wave-local init: T zero (h0 == 0, MFMAs on zeros == r8 exactly);
  // P zero except bias col 9 = 1.0 ----
  for (int i = lane; i < kRowsPerWave * kTStride; i += 64) Tw[i] = (_Float16)0.0f;
  for (int i = lane; i < kRowsPerWave * kPStride; i += 64)
    Pw[i] = ((i % kPStride) == kIn) ? (_Float16)1.0f : (_Float16)0.0f;

  // ---- cell state: c_st[ct*4+j] <-> (row rw0+quad*4+j, unit ct*16+half) ----
  float c_st[16];
#pragma unroll
  for (int i = 0; i < 16; ++i) c_st[i] = 0.0f;

  // ---- cooperative weight stage: thread n loads weight row n (256 = 4H) ----
  // PRE-SCALED exactly as r8: sigmoid gates (i,f,o) x log2e, tanh gate (g)
  // x 2*log2e; bias in the k=73 column (A supplies 1.0 at k-slot 9).
  auto load_W = [&](const void* Whh, const void* Wih, const void* bv) {
    const int n = tid;
    const float scale = ((n >> 6) == 2) ? k2Log2e : kLog2e;
    _Float16* wr = &Wl[n * kWStride];
#pragma unroll 4
    for (int k = 0; k < kH; ++k)
      wr[k] = (_Float16)(scale * ldf(Whh, n * kH + k, isbf));
#pragma unroll
    for (int k = 0; k < 16; ++k) {
      float v = 0.0f;
      if (k < kIn) v = ldf(Wih, n * kIn + k, isbf);
      else if (k == kIn) v = ldf(bv, n, isbf);  // bias column
      wr[kH + k] = (_Float16)(scale * v);
    }
  };

  // ---- x fragment from global src (encoder + decoder step 1) ----
  // lane (quad,half) supplies A[row=half][k=quad*4+e]: k 0..8 = x, k 9 = 1.0.
  auto a2_src = [&](int s) -> frag_a2 {
    frag_a2 f = {(_Float16)0.f, (_Float16)0.f, (_Float16)0.f, (_Float16)0.f};
    const int base = (rw0 + half) * (kSrcLen * kIn) + s * kIn;
    if (quad < 2) {
#pragma unroll
      for (int e = 0; e < 4; ++e) f[e] = (_Float16)ldf(src, base + quad * 4 + e, isbf);
    } else if (quad == 2) {
      f[0] = (_Float16)ldf(src, base + 8, isbf);
      f[1] = (_Float16)1.0f;  // bias slot (k==9)
    }
    return f;
  };

  // ---- one LSTM step for this wave's 16 rows; NO barrier anywhere ----
  // A-frags (h_prev) read once (same A for all 16 n-tiles); 16 tiles =
  // 4 units-chunks (ct) x 4 gates; activations r8-verbatim.
  auto lstm_step = [&](frag_a2 a2) {
    const int tbase = half * kTStride + quad * 8;
    const frag_a2 t0 = *(const frag_a2*)&Tw[tbase];
    const frag_a2 t1 = *(const frag_a2*)&Tw[tbase + 4];
    const frag_a2 t2 = *(const frag_a2*)&Tw[tbase + 32];
    const frag_a2 t3 = *(const frag_a2*)&Tw[tbase + 36];
    const frag_a a0 = __builtin_shufflevector(t0, t1, 0, 1, 2, 3, 4, 5, 6, 7);
    const frag_a a1 = __builtin_shufflevector(t2, t3, 0, 1, 2, 3, 4, 5, 6, 7);
#pragma unroll 1
    for (int ct = 0; ct < 4; ++ct) {
      frag_cd acc[4];
#pragma unroll
      for (int g = 0; g < 4; ++g) {
        const int nb = (g * kH + ct * 16 + half) * kWStride;
        const frag_a b0 = *(const frag_a*)&Wl[nb + quad * 8];
        const frag_a b1 = *(const frag_a*)&Wl[nb + 32 + quad * 8];
        const frag_a2 b2 = *(const frag_a2*)&Wl[nb + 64 + quad * 4];
        frag_cd a = {0.f, 0.f, 0.f, 0.f};
        a = __builtin_amdgcn_mfma_f32_16x16x32_f16(a0, b0, a, 0, 0, 0);
        a = __builtin_amdgcn_mfma_f32_16x16x32_f16(a1, b1, a, 0, 0, 0);
        a = __builtin_amdgcn_mfma_f32_16x16x16f16(a2, b2, a, 0, 0, 0);
        acc[g] = a;
      }
      // acc[0..3][j] = (gi,gf,gg,go) for (row quad*4+j, unit ct*16+half)
#pragma unroll
      for (int j = 0; j < 4; ++j) {
        const float gi = acc[0][j];
        const float gf = acc[1][j];
        const float gg = acc[2][j];
        const float go = acc[3][j];
        const float ei = exp2_f(-gi);
        const float ef = exp2_f(-gf);
        const float eg = exp2_f(gg);
        const float eo = exp2_f(-go);
        const float c_old = c_st[ct * 4 + j];
        const float p1 = (1.0f + ei) * (eg + 1.0f);
        const float q = (eg - 1.0f) * (1.0f + ef);
        const float num = fmaf(c_old, p1, q);
        const float c = num * fast_rcp(p1 * (1.0f + ef));
        c_st[ct * 4 + j] = c;
        const float t = exp2_f(c * k2Log2e);
        const float h = (t - 1.0f) * fast_rcp((1.0f + eo) * (t + 1.0f));
        Tw[(quad * 4 + j) * kTStride + ct * 16 + half] = (_Float16)h;
      }
    }
  };

  // ================= ENCODER =================
  load_W(enc_Whh, enc_Wih, enc_b);
  __syncthreads();  // enc weights visible

#pragma unroll 1
  for (int s = 0; s < kSrcLen; ++s) lstm_step(a2_src(s));

  // ================= DECODER =================
  __syncthreads();  // all waves done READING enc weights before overwrite
  load_W(dec_Whh, dec_Wih, dec_b);
  // fc fragments in registers (r8-identical values)
  frag_a fm0, fm1;
#pragma unroll
  for (int j = 0; j < 8; ++j) {
    fm0[j] = (half < kIn) ? (_Float16)ldf(fc_W, half * kH + j + quad * 8, isbf)
                          : (_Float16)0.0f;
    fm1[j] = (half < kIn) ? (_Float16)ldf(fc_W, half * kH + 32 + quad * 8 + j, isbf)
                          : (_Float16)0.0f;
  }
  const float fcb = (half < kIn) ? ldf(fc_b, half, isbf) : 0.0f;
  __syncthreads();  // dec weights visible

  // fc head: reads h_new from Tw (same-wave write -> lgkmcnt ordering),
  // writes pred to out and into the P feedback panel. All wave-local.
  auto fc_head = [&](int t) {
    const int tbase = half * kTStride + quad * 8;
    const frag_a2 t0 = *(const frag_a2*)&Tw[tbase];
    const frag_a2 t1 = *(const frag_a2*)&Tw[tbase + 4];
    const frag_a2 t2 = *(const frag_a2*)&Tw[tbase + 32];
    const frag_a2 t3 = *(const frag_a2*)&Tw[tbase + 36];
    const frag_a a0 = __builtin_shufflevector(t0, t1, 0, 1, 2, 3, 4, 5, 6, 7);
    const frag_a a1 = __builtin_shufflevector(t2, t3, 0, 1, 2, 3, 4, 5, 6, 7);
    frag_cd p = {fcb, fcb, fcb, fcb};
    p = __builtin_amdgcn_mfma_f32_16x16x32_f16(a0, fm0, p, 0, 0, 0);
    p = __builtin_amdgcn_mfma_f32_16x16x32_f16(a1, fm1, p, 0, 0, 0);
    if (half < kIn) {
#pragma unroll
      for (int j = 0; j < 4; ++j) {
        const int rr = quad * 4 + j;  // local row
        const float pred = p[j];
        const int oidx = (rw0 + rr) * kOutW + t * kIn + half;
        if (isbf) ((__hip_bfloat16*)out)[oidx] = __float2bfloat16(pred);
        else ((float*)out)[oidx] = pred;
        Pw[rr * kPStride + half] = (_Float16)pred;  // feedback x
      }
    }
  };

  // decoder step 1: x_last = src[:, -1, :]
  lstm_step(a2_src(kSrcLen - 1));
  fc_head(0);

#pragma unroll 1
  for (int t = 1; t < kPredLen; ++t) {
    // a2 from the P panel: lane (quad,half) reads pred[row=half][k=quad*4+e]
    // (k==9 -> 1.0 bias, k 10..15 -> 0, set at init and never overwritten)
    const frag_a2 a2 = *(const frag_a2*)&Pw[half * kPStride + quad * 4];
    lstm_step(a2);
    fc_head(t);
  }
}

extern "C" void kernel_launch(void* const* d_in, const int* in_sizes, int n_in,
                              void* d_out, int out_size, void* d_ws, size_t ws_size,
                              hipStream_t stream) {
  (void)n_in; (void)ws_size; (void)out_size;
  int* flag = (int*)d_ws;

  hipLaunchKernelGGL(detect_dtype_kernel, dim3(1), dim3(64), 0, stream,
                     (const uint16_t*)d_in[0], flag);

  const int b_total = in_sizes[0] / (kSrcLen * kIn);
  const int grid = b_total / kRows;  // B=65536 -> 1024 blocks

  hipLaunchKernelGGL(lstm_seq2seq_kernel, dim3(grid), dim3(kThreads), 0, stream,
                     d_in[0], d_in[1], d_in[2], d_in[3], d_in[4], d_in[5],
                     d_in[6], d_in[7], d_in[8], d_out, flag);
}

// Round 13
// 210.718 us; speedup vs baseline: 1.2047x; 1.2047x over previous
//
#include <hip/hip_runtime.h>
#include <hip/hip_bf16.h>
#include <stdint.h>

namespace {
constexpr int kH = 64;
constexpr int kIn = 9;
constexpr int kSrcLen = 7;
constexpr int kPredLen = 10;
constexpr int kRows = 64;        // batch rows per block
constexpr int kThreads = 256;    // 4 waves
constexpr int kOutW = kPredLen * kIn;  // 90
// A (h part): fragment-contiguous f16, 8 k-blocks (k 0..63), element
// (blk,row,e) at (blk*64+row)*8+e. x/bias live in a separate 16-wide panel
// ax[row][e]: e 0..8 = x, e 9 = 1.0 (bias), 10..15 = 0 (K-tile 2 = 16x16x16).
constexpr int kABlk = 8;
constexpr int kASz = kABlk * kRows * 8;   // 4096 halves = 8192 B per buffer
constexpr int kAxSz = kRows * 16;         // 1024 halves = 2048 B per buffer

constexpr float kLog2e = 1.4426950408889634f;
constexpr float k2Log2e = 2.8853900817779268f;

typedef __attribute__((ext_vector_type(8))) _Float16 frag_a;   // K=32 frag (4 VGPRs)
typedef __attribute__((ext_vector_type(4))) _Float16 frag_a2;  // K=16 frag (2 VGPRs)
typedef __attribute__((ext_vector_type(4))) float frag_cd;     // 4 fp32 acc

__device__ __forceinline__ float fast_rcp(float x) { return __builtin_amdgcn_rcpf(x); }
__device__ __forceinline__ float exp2_f(float x) { return __builtin_amdgcn_exp2f(x); }

__device__ __forceinline__ float ldf(const void* p, int i, int isbf) {
  if (isbf) {
    uint32_t w = ((uint32_t)((const uint16_t*)p)[i]) << 16;
    float f; __builtin_memcpy(&f, &w, 4); return f;
  }
  return ((const float*)p)[i];
}
}  // namespace

// Detect whether inputs are bf16 or fp32 by sampling src.
extern "C" __global__ void detect_dtype_kernel(const uint16_t* __restrict__ src_u16,
                                               int* __restrict__ flag) {
  const int t = threadIdx.x;
  int bad = 0;
  for (int i = t; i < 256; i += 64) {
    const uint16_t u = src_u16[i];
    const uint32_t e = (u >> 7) & 0xFF;
    const int plausible = (u == 0) || (e >= 100 && e <= 150);
    bad += !plausible;
  }
#pragma unroll
  for (int off = 32; off; off >>= 1) bad += __shfl_down(bad, off, 64);
  if (t == 0) *flag = (bad < 64) ? 1 : 0;
}

extern "C" __global__ void __launch_bounds__(kThreads)
// CHAMPION (r8, 147us kernel / 212us bench, absmax 3.9e-3) — restored after
// r9-r12 tested and eliminated every remaining lever:
//   occupancy: register wall — demand ~124 of the 128-unified (4,4) budget;
//     every smaller budget spilled 0.2-1.5 GB scratch (r1/r3/r6/r7).
//   LDS conflicts: NOT on the critical path — XOR-swizzle (r10) and +1-pad
//     (r11) both left conflicts ~1.35e7 and ADDED 12-18us.
//   barriers: NOT dominant — barrier-free row-decomp (r12) removed all 27
//     but paid +47us in weight-fragment LDS reads on the MFMA path.
//   scheduling: intra-step read hoist/rotate (r9) broke correctness.
// Wins baked in: log2e pre-scaled f16 weights (no mul before v_exp) and
// fused-rcp activations (7 trans/element vs 10): c' and h each use ONE rcp.
// ACCURACY LEDGER: non-folded decoder robust at 3.9e-3; folded-decoder
// family abandoned (threshold roulette at 1.42e-2).
__attribute__((amdgpu_waves_per_eu(4, 4)))
lstm_seq2seq_kernel(const void* __restrict__ src,
                    const void* __restrict__ enc_Wih,
                    const void* __restrict__ enc_Whh,
                    const void* __restrict__ enc_b,
                    const void* __restrict__ dec_Wih,
                    const void* __restrict__ dec_Whh,
                    const void* __restrict__ dec_b,
                    const void* __restrict__ fc_W,
                    const void* __restrict__ fc_b,
                    void* __restrict__ out,
                    const int* __restrict__ flag) {
  __shared__ __align__(16) _Float16 a_m[2][kASz];   // h part, 2 x 8192 B
  __shared__ __align__(16) _Float16 ax[2][kAxSz];   // x|bias panel, 2 x 2048 B

  const int tid = threadIdx.x;
  const int lane = tid & 63;
  const int wave = tid >> 6;
  const int quad = lane >> 4;
  const int half = lane & 15;
  const int row0 = blockIdx.x * kRows;
  const int isbf = *flag;  // grid-uniform
  const int col = wave * 16 + half;  // hidden column owned in activation phase

  // ---- init: h buffers zero; ax zero except bias column e=9 = 1.0 ----
  for (int i = tid; i < kASz; i += kThreads) {
    a_m[0][i] = (_Float16)0.0f;
    a_m[1][i] = (_Float16)0.0f;
  }
  for (int i = tid; i < kAxSz; i += kThreads) {
    const _Float16 v = ((i & 15) == 9) ? (_Float16)1.0f : (_Float16)0.0f;
    ax[0][i] = v;
    ax[1][i] = v;
  }
  __syncthreads();

  // per-thread encoder staging slots (fixed across steps): items tid, tid+256,
  // tid+512 of the 576-element x panel; r = item/9, i = item%9.
  const int it1_on = (tid + 256 < kRows * kIn);
  const int it2_on = (tid + 512 < kRows * kIn);
  const int r_0 = tid / kIn, i_0 = tid - r_0 * kIn;
  const int r_1 = (tid + 256) / kIn, i_1 = (tid + 256) - r_1 * kIn;
  const int r_2 = (tid + 512) / kIn, i_2 = (tid + 512) - r_2 * kIn;
  const int lds0 = r_0 * 16 + i_0;
  const int lds1 = r_1 * 16 + i_1;
  const int lds2 = r_2 * 16 + i_2;
  const int g0 = (row0 + r_0) * (kSrcLen * kIn) + i_0;
  const int g1 = (row0 + r_1) * (kSrcLen * kIn) + i_1;
  const int g2 = (row0 + r_2) * (kSrcLen * kIn) + i_2;

  // stage x(step 0) into buf 0
  ax[0][lds0] = (_Float16)ldf(src, g0, isbf);
  if (it1_on) ax[0][lds1] = (_Float16)ldf(src, g1, isbf);
  if (it2_on) ax[0][lds2] = (_Float16)ldf(src, g2, isbf);

  // ---- persistent per-thread state ----
  float c_st[16];
#pragma unroll
  for (int i = 0; i < 16; ++i) c_st[i] = 0.0f;

  // B fragments: nt = GATE TYPE (i,f,g,o), col = wave*16+half.
  // bm0/bm1[nt] = K-tiles 0,1 (Whh, K=32 each); bm2[nt] = K-tile 2 (Wih+bias, K=16).
  // PRE-SCALED: sigmoid gates (i,f,o) by log2e, tanh gate (g) by 2*log2e
  // -> activations use raw v_exp_f32 (exp2) with no pre-multiply.
  frag_a bm0[4], bm1[4];
  frag_a2 bm2[4];
  frag_a fm[2];
  float fcb = 0.0f;

  auto load_gate_frags = [&](const void* Whh, const void* Wih, const void* bv) {
#pragma unroll
    for (int nt = 0; nt < 4; ++nt) {
      const float scale = (nt == 2) ? k2Log2e : kLog2e;
      const int n = nt * kH + col;
      frag_a f0, f1;
#pragma unroll
      for (int j = 0; j < 8; ++j) {
        f0[j] = (_Float16)(scale * ldf(Whh, n * kH + (quad * 8 + j), isbf));
        f1[j] = (_Float16)(scale * ldf(Whh, n * kH + (32 + quad * 8 + j), isbf));
      }
      bm0[nt] = f0;
      bm1[nt] = f1;
      frag_a2 f2;
#pragma unroll
      for (int j = 0; j < 4; ++j) {
        const int k2 = quad * 4 + j;  // 0..15, global k = 64 + k2
        float v = 0.0f;
        if (k2 < kIn) v = ldf(Wih, n * kIn + k2, isbf);
        else if (k2 == kIn) v = ldf(bv, n, isbf);  // bias column (A=1)
        f2[j] = (_Float16)(scale * v);
      }
      bm2[nt] = f2;
    }
  };

  // One LSTM step: read A from buf[cur], write h into buf[cur^1]. No barrier.
  // Gates arrive PRE-SCALED: gi,gf,go by L, gg by 2L. Fused-rcp activations:
  //   c' = [c*(1+ei)(eg+1) + (eg-1)(1+ef)] / [(1+ei)(eg+1)(1+ef)]   (1 rcp)
  //   h  = (t-1) / [(1+eo)(t+1)],  t = 2^(2L*c')                    (1 rcp)
  // Algebraically identical to sigmoid/tanh forms; 7 trans vs 10.
  auto lstm_step = [&](int cur) {
#pragma unroll 1
    for (int ch = 0; ch < 4; ++ch) {
      const int r = ch * 16 + half;
      const frag_a a0 = *(const frag_a*)&a_m[cur][((0 * 4 + quad) * kRows + r) * 8];
      const frag_a a1 = *(const frag_a*)&a_m[cur][((1 * 4 + quad) * kRows + r) * 8];
      const frag_a2 a2 = *(const frag_a2*)&ax[cur][r * 16 + quad * 4];

      frag_cd acc[4];
#pragma unroll
      for (int nt = 0; nt < 4; ++nt) {
        frag_cd a = {0.f, 0.f, 0.f, 0.f};
        a = __builtin_amdgcn_mfma_f32_16x16x32_f16(a0, bm0[nt], a, 0, 0, 0);
        a = __builtin_amdgcn_mfma_f32_16x16x32_f16(a1, bm1[nt], a, 0, 0, 0);
        a = __builtin_amdgcn_mfma_f32_16x16x16f16(a2, bm2[nt], a, 0, 0, 0);
        acc[nt] = a;
      }

      // activations fully in registers: acc[0..3][j] = (gi,gf,gg,go) for
      // (row = ch*16 + quad*4 + j, col)
#pragma unroll
      for (int j = 0; j < 4; ++j) {
        const float gi = acc[0][j];
        const float gf = acc[1][j];
        const float gg = acc[2][j];
        const float go = acc[3][j];
        const float ei = exp2_f(-gi);
        const float ef = exp2_f(-gf);
        const float eg = exp2_f(gg);
        const float eo = exp2_f(-go);
        const float c_old = c_st[ch * 4 + j];
        const float p1 = (1.0f + ei) * (eg + 1.0f);
        const float q = (eg - 1.0f) * (1.0f + ef);
        const float num = fmaf(c_old, p1, q);
        const float c = num * fast_rcp(p1 * (1.0f + ef));
        c_st[ch * 4 + j] = c;
        const float t = exp2_f(c * k2Log2e);
        const float h = (t - 1.0f) * fast_rcp((1.0f + eo) * (t + 1.0f));
        const int rr = ch * 16 + quad * 4 + j;
        a_m[cur ^ 1][(((col >> 3) * kRows) + rr) * 8 + (col & 7)] = (_Float16)h;
      }
    }
  };

  // ================= ENCODER =================
  load_gate_frags(enc_Whh, enc_Wih, enc_b);
  __syncthreads();  // x(0) + init visible

  int cur = 0;
#pragma unroll 1
  for (int s = 0; s < kSrcLen; ++s) {
    // prefetch next-step x BEFORE the step so L2 latency overlaps compute
    const int ns = (s + 1 < kSrcLen) ? s + 1 : kSrcLen - 1;
    const int off = ns * kIn;
    const float x0 = ldf(src, g0 + off, isbf);
    const float x1 = it1_on ? ldf(src, g1 + off, isbf) : 0.0f;
    const float x2 = it2_on ? ldf(src, g2 + off, isbf) : 0.0f;

    lstm_step(cur);

    ax[cur ^ 1][lds0] = (_Float16)x0;
    if (it1_on) ax[cur ^ 1][lds1] = (_Float16)x1;
    if (it2_on) ax[cur ^ 1][lds2] = (_Float16)x2;
    __syncthreads();
    cur ^= 1;
  }

  // ================= DECODER =================
  load_gate_frags(dec_Whh, dec_Wih, dec_b);
  // fc B fragments (K-tiles 0,1 = h only; bias via acc init); B cols 0..8.
  // fc weights NOT scaled (no activation on the head).
#pragma unroll
  for (int kt = 0; kt < 2; ++kt) {
    frag_a f;
#pragma unroll
    for (int j = 0; j < 8; ++j) {
      const int k = kt * 32 + quad * 8 + j;
      f[j] = (half < kIn) ? (_Float16)ldf(fc_W, half * kH + k, isbf) : (_Float16)0.0f;
    }
    fm[kt] = f;
  }
  fcb = (half < kIn) ? ldf(fc_b, half, isbf) : 0.0f;

#pragma unroll 1
  for (int t = 0; t < kPredLen; ++t) {
    lstm_step(cur);
    __syncthreads();
    cur ^= 1;

    // ---- fc head: wave w handles rows [w*16, w*16+16) of buf[cur] ----
    const int r = wave * 16 + half;
    const frag_a a0 = *(const frag_a*)&a_m[cur][((0 * 4 + quad) * kRows + r) * 8];
    const frag_a a1 = *(const frag_a*)&a_m[cur][((1 * 4 + quad) * kRows + r) * 8];
    frag_cd p = {fcb, fcb, fcb, fcb};
    p = __builtin_amdgcn_mfma_f32_16x16x32_f16(a0, fm[0], p, 0, 0, 0);
    p = __builtin_amdgcn_mfma_f32_16x16x32_f16(a1, fm[1], p, 0, 0, 0);

    if (half < kIn) {
#pragma unroll
      for (int j = 0; j < 4; ++j) {
        const int rr = wave * 16 + quad * 4 + j;
        const float pred = p[j];
        const int oidx = (row0 + rr) * kOutW + t * kIn + half;
        if (isbf) {
          ((__hip_bfloat16*)out)[oidx] = __float2bfloat16(pred);
        } else {
          ((float*)out)[oidx] = pred;
        }
        // feedback x into the panel the next step reads (bias col untouched)
        ax[cur][rr * 16 + half] = (_Float16)pred;
      }
    }
    __syncthreads();
  }
}

extern "C" void kernel_launch(void* const* d_in, const int* in_sizes, int n_in,
                              void* d_out, int out_size, void* d_ws, size_t ws_size,
                              hipStream_t stream) {
  (void)n_in; (void)ws_size; (void)out_size;
  int* flag = (int*)d_ws;

  hipLaunchKernelGGL(detect_dtype_kernel, dim3(1), dim3(64), 0, stream,
                     (const uint16_t*)d_in[0], flag);

  const int b_total = in_sizes[0] / (kSrcLen * kIn);
  const int grid = b_total / kRows;  // B=65536 -> 1024 blocks = 4 per CU

  hipLaunchKernelGGL(lstm_seq2seq_kernel, dim3(grid), dim3(kThreads), 0, stream,
                     d_in[0], d_in[1], d_in[2], d_in[3], d_in[4], d_in[5],
                     d_in[6], d_in[7], d_in[8], d_out, flag);
}